// Round 4
// baseline (46.503 us; speedup 1.0000x reference)
//
#include <hip/hip_runtime.h>
#include <hip/hip_bf16.h>

typedef __attribute__((ext_vector_type(8))) short bf16x8;
typedef __attribute__((ext_vector_type(4))) float f32x4;

static constexpr int Bb = 64;
static constexpr int Qq = 32;
static constexpr int LD = 4096;
static constexpr int Dd = 128;
static constexpr int SPLITS = 16;          // L-chunks per batch -> 1024 blocks
static constexpr int CHUNK = LD / SPLITS;  // 256 tokens per block
static constexpr int NWAVE = 8;            // 512 threads; wave pairs share tokens
static constexpr int NRANGE = NWAVE / 2;   // 4 token sub-ranges per block
static constexpr int TPW = CHUNK / NRANGE; // 64 tokens per wave
static constexpr int LTILES = TPW / 16;    // 4 MFMA l-tiles per wave

__device__ __forceinline__ short f2bf(float f) {
  __hip_bfloat16 h = __float2bfloat16(f);
  return *reinterpret_cast<short*>(&h);
}

__device__ __forceinline__ bf16x8 cvt8(float4 a, float4 b) {
  bf16x8 v;
  v[0] = f2bf(a.x); v[1] = f2bf(a.y); v[2] = f2bf(a.z); v[3] = f2bf(a.w);
  v[4] = f2bf(b.x); v[5] = f2bf(b.y); v[6] = f2bf(b.z); v[7] = f2bf(b.w);
  return v;
}

// Stage 1: 32 waves/CU streaming kernel. Each wave owns ONE 16-query M-tile
// (afrag = 16 VGPR) and a 64-token range; the wave pair sharing a range reads
// the same doc lines (L1-absorbed). VGPR target <=64 for 8 waves/SIMD.
__global__ __launch_bounds__(512, 8) void maxsim_stage1(
    const float* __restrict__ qe, const float* __restrict__ de,
    float* __restrict__ pmax) {
  // XCD-chunked swizzle (grid 1024 = 8 XCDs x 128): each XCD gets 8 whole
  // batches -> its Q working set (128 KB) stays L2-resident.
  const int blk = (blockIdx.x & 7) * (Bb * SPLITS / 8) + (blockIdx.x >> 3);
  const int b    = blk / SPLITS;
  const int s    = blk % SPLITS;
  const int wave = threadIdx.x >> 6;
  const int mt   = wave & 1;        // which 16-query M-tile this wave owns
  const int rng  = wave >> 1;       // which 64-token sub-range
  const int lane = threadIdx.x & 63;
  const int lcol = lane & 15;       // MFMA column slot
  const int lgrp = lane >> 4;       // MFMA k-group

  const float* __restrict__ qb = qe + (size_t)b * Qq * Dd;
  const float* __restrict__ db = de + (size_t)b * LD * Dd;

  // A fragment: one M-tile of 16 query rows. Same lane->k rule as B, so any
  // k-slot permutation cancels in the dot product.
  bf16x8 afrag[4];
#pragma unroll
  for (int kb = 0; kb < 4; ++kb) {
    const float* p = qb + (size_t)(mt * 16 + lcol) * Dd + kb * 32 + lgrp * 8;
    afrag[kb] = cvt8(*reinterpret_cast<const float4*>(p),
                     *reinterpret_cast<const float4*>(p + 4));
  }

  float mx[4];
#pragma unroll
  for (int i = 0; i < 4; ++i) mx[i] = -3.4e38f;

  const int tok0 = s * CHUNK + rng * TPW;
  const float* __restrict__ lanebase = db + (size_t)(tok0 + lcol) * Dd + lgrp * 8;

#pragma unroll
  for (int lt = 0; lt < LTILES; ++lt) {
    const float* tb = lanebase + (size_t)lt * 16 * Dd;
    f32x4 acc = {0.f, 0.f, 0.f, 0.f};
#pragma unroll
    for (int kb = 0; kb < 4; ++kb) {
      bf16x8 bfrag = cvt8(*reinterpret_cast<const float4*>(tb + kb * 32),
                          *reinterpret_cast<const float4*>(tb + kb * 32 + 4));
      acc = __builtin_amdgcn_mfma_f32_16x16x32_bf16(afrag[kb], bfrag, acc, 0, 0, 0);
    }
    // C/D layout (m89-verified): col = lane&15 (doc token), row = lgrp*4+i (query).
#pragma unroll
    for (int i = 0; i < 4; ++i) mx[i] = fmaxf(mx[i], acc[i]);
  }

  // Max over the 16 doc-token columns = butterfly over low 4 lane bits.
#pragma unroll
  for (int off = 1; off < 16; off <<= 1)
#pragma unroll
    for (int i = 0; i < 4; ++i) mx[i] = fmaxf(mx[i], __shfl_xor(mx[i], off));

  __shared__ float smax[NWAVE][16];
  if (lcol == 0) {
#pragma unroll
    for (int i = 0; i < 4; ++i) smax[wave][lgrp * 4 + i] = mx[i];
  }
  __syncthreads();
  if (threadIdx.x < Qq) {
    const int qi = threadIdx.x;
    const int qmt = qi >> 4;       // which M-tile this query sits in
    const int qr  = qi & 15;
    float m = -3.4e38f;
#pragma unroll
    for (int r = 0; r < NRANGE; ++r)
      m = fmaxf(m, smax[r * 2 + qmt][qr]);
    pmax[((size_t)b * SPLITS + s) * Qq + qi] = m;
  }
}

// Stage 2: out[b] = sum_q max_s pmax[b][s][q]. One wave per batch.
__global__ __launch_bounds__(64) void maxsim_stage2(
    const float* __restrict__ pmax, float* __restrict__ out) {
  const int b = blockIdx.x;
  const int lane = threadIdx.x;
  float v = 0.f;
  if (lane < Qq) {
    float m = -3.4e38f;
#pragma unroll
    for (int s = 0; s < SPLITS; ++s)
      m = fmaxf(m, pmax[((size_t)b * SPLITS + s) * Qq + lane]);
    v = m;
  }
#pragma unroll
  for (int off = 1; off < 64; off <<= 1) v += __shfl_xor(v, off);
  if (lane == 0) out[b] = v;
}

extern "C" void kernel_launch(void* const* d_in, const int* in_sizes, int n_in,
                              void* d_out, int out_size, void* d_ws, size_t ws_size,
                              hipStream_t stream) {
  const float* qe = (const float*)d_in[0];  // [64,32,128] f32
  const float* de = (const float*)d_in[1];  // [64,4096,128] f32
  float* out  = (float*)d_out;              // [64] f32
  float* pmax = (float*)d_ws;               // [64][16][32] f32 = 128 KB

  maxsim_stage1<<<Bb * SPLITS, 512, 0, stream>>>(qe, de, pmax);
  maxsim_stage2<<<Bb, 64, 0, stream>>>(pmax, out);
}

// Round 5
// 31.685 us; speedup vs baseline: 1.4677x; 1.4677x over previous
//
#include <hip/hip_runtime.h>
#include <hip/hip_bf16.h>

typedef __attribute__((ext_vector_type(8))) short bf16x8;
typedef __attribute__((ext_vector_type(4))) float f32x4;

static constexpr int Bb = 64;
static constexpr int Qq = 32;
static constexpr int LD = 4096;
static constexpr int Dd = 128;
static constexpr int SPLITS = 16;          // L-chunks per batch -> 1024 blocks (4/CU)
static constexpr int CHUNK = LD / SPLITS;  // 256 tokens per block
static constexpr int NWAVE = 4;            // 256 threads
static constexpr int TPW = CHUNK / NWAVE;  // 64 tokens per wave (distinct, no sharing)
static constexpr int LTILES = TPW / 16;    // 4 MFMA l-tiles per wave

__device__ __forceinline__ short f2bf(float f) {
  __hip_bfloat16 h = __float2bfloat16(f);
  return *reinterpret_cast<short*>(&h);
}

__device__ __forceinline__ bf16x8 cvt8(float4 a, float4 b) {
  bf16x8 v;
  v[0] = f2bf(a.x); v[1] = f2bf(a.y); v[2] = f2bf(a.z); v[3] = f2bf(a.w);
  v[4] = f2bf(b.x); v[5] = f2bf(b.y); v[6] = f2bf(b.z); v[7] = f2bf(b.w);
  return v;
}

// Stage 1: R1's proven per-wave structure (each wave owns distinct tokens,
// each loaded doc fragment feeds BOTH M-tile MFMAs - no duplicate reads),
// at 2x the block count: 1024 blocks = 4 blocks/CU = 16 waves/CU.
__global__ __launch_bounds__(256) void maxsim_stage1(
    const float* __restrict__ qe, const float* __restrict__ de,
    float* __restrict__ pmax) {
  const int blk  = blockIdx.x;
  const int b    = blk / SPLITS;
  const int s    = blk % SPLITS;
  const int wave = threadIdx.x >> 6;
  const int lane = threadIdx.x & 63;
  const int lcol = lane & 15;   // MFMA column slot (doc token within tile; q row for A)
  const int lgrp = lane >> 4;   // MFMA k-group

  const float* __restrict__ qb = qe + (size_t)b * Qq * Dd;
  const float* __restrict__ db = de + (size_t)b * LD * Dd;

  // A fragments (query tile, M=32 -> 2 M-tiles of 16), in registers all kernel.
  // Same lane->k rule for A and B, so any k-slot permutation cancels.
  bf16x8 afrag[2][4];
#pragma unroll
  for (int mt = 0; mt < 2; ++mt)
#pragma unroll
    for (int kb = 0; kb < 4; ++kb) {
      const float* p = qb + (size_t)(mt * 16 + lcol) * Dd + kb * 32 + lgrp * 8;
      afrag[mt][kb] = cvt8(*reinterpret_cast<const float4*>(p),
                           *reinterpret_cast<const float4*>(p + 4));
    }

  float mx0[4], mx1[4];
#pragma unroll
  for (int i = 0; i < 4; ++i) { mx0[i] = -3.4e38f; mx1[i] = -3.4e38f; }

  const int tok0 = s * CHUNK + wave * TPW;
  // Per-lane base: row = tok0 + lcol, k-slice = lgrp*8. Tile lt adds 16 rows.
  const float* __restrict__ lanebase = db + (size_t)(tok0 + lcol) * Dd + lgrp * 8;

  // Prefetch pipeline: nraw holds the NEXT tile's raw floats; convert current,
  // issue next loads, then MFMA - loads overlap cvt+MFMA of current tile.
  float4 nraw[8];
#pragma unroll
  for (int kb = 0; kb < 4; ++kb) {
    nraw[2 * kb]     = *reinterpret_cast<const float4*>(lanebase + kb * 32);
    nraw[2 * kb + 1] = *reinterpret_cast<const float4*>(lanebase + kb * 32 + 4);
  }

#pragma unroll
  for (int lt = 0; lt < LTILES; ++lt) {
    bf16x8 bfrag[4];
#pragma unroll
    for (int kb = 0; kb < 4; ++kb)
      bfrag[kb] = cvt8(nraw[2 * kb], nraw[2 * kb + 1]);
    if (lt + 1 < LTILES) {
      const float* nb = lanebase + (size_t)(lt + 1) * 16 * Dd;
#pragma unroll
      for (int kb = 0; kb < 4; ++kb) {
        nraw[2 * kb]     = *reinterpret_cast<const float4*>(nb + kb * 32);
        nraw[2 * kb + 1] = *reinterpret_cast<const float4*>(nb + kb * 32 + 4);
      }
    }
    f32x4 acc0 = {0.f, 0.f, 0.f, 0.f};
    f32x4 acc1 = {0.f, 0.f, 0.f, 0.f};
#pragma unroll
    for (int kb = 0; kb < 4; ++kb) {
      acc0 = __builtin_amdgcn_mfma_f32_16x16x32_bf16(afrag[0][kb], bfrag[kb], acc0, 0, 0, 0);
      acc1 = __builtin_amdgcn_mfma_f32_16x16x32_bf16(afrag[1][kb], bfrag[kb], acc1, 0, 0, 0);
    }
    // C/D layout (m89-verified): col = lane&15 (doc token), row = lgrp*4 + i (query).
#pragma unroll
    for (int i = 0; i < 4; ++i) {
      mx0[i] = fmaxf(mx0[i], acc0[i]);
      mx1[i] = fmaxf(mx1[i], acc1[i]);
    }
  }

  // Max over doc-token columns = butterfly over the low 4 lane bits.
#pragma unroll
  for (int off = 1; off < 16; off <<= 1) {
#pragma unroll
    for (int i = 0; i < 4; ++i) {
      mx0[i] = fmaxf(mx0[i], __shfl_xor(mx0[i], off));
      mx1[i] = fmaxf(mx1[i], __shfl_xor(mx1[i], off));
    }
  }

  __shared__ float smax[NWAVE][Qq];
  if (lcol == 0) {
#pragma unroll
    for (int i = 0; i < 4; ++i) {
      smax[wave][lgrp * 4 + i]      = mx0[i];
      smax[wave][16 + lgrp * 4 + i] = mx1[i];
    }
  }
  __syncthreads();
  if (threadIdx.x < Qq) {
    const int qi = threadIdx.x;
    float m = fmaxf(fmaxf(smax[0][qi], smax[1][qi]),
                    fmaxf(smax[2][qi], smax[3][qi]));
    pmax[((size_t)b * SPLITS + s) * Qq + qi] = m;
  }
}

// Stage 2: out[b] = sum_q max_s pmax[b][s][q]. One wave per batch.
__global__ __launch_bounds__(64) void maxsim_stage2(
    const float* __restrict__ pmax, float* __restrict__ out) {
  const int b = blockIdx.x;
  const int lane = threadIdx.x;
  float v = 0.f;
  if (lane < Qq) {
    float m = -3.4e38f;
#pragma unroll
    for (int s = 0; s < SPLITS; ++s)
      m = fmaxf(m, pmax[((size_t)b * SPLITS + s) * Qq + lane]);
    v = m;
  }
#pragma unroll
  for (int off = 1; off < 64; off <<= 1) v += __shfl_xor(v, off);
  if (lane == 0) out[b] = v;
}

extern "C" void kernel_launch(void* const* d_in, const int* in_sizes, int n_in,
                              void* d_out, int out_size, void* d_ws, size_t ws_size,
                              hipStream_t stream) {
  const float* qe = (const float*)d_in[0];  // [64,32,128] f32
  const float* de = (const float*)d_in[1];  // [64,4096,128] f32
  float* out  = (float*)d_out;              // [64] f32
  float* pmax = (float*)d_ws;               // [64][16][32] f32 = 128 KB

  maxsim_stage1<<<Bb * SPLITS, 256, 0, stream>>>(qe, de, pmax);
  maxsim_stage2<<<Bb, 64, 0, stream>>>(pmax, out);
}

// Round 6
// 28.577 us; speedup vs baseline: 1.6273x; 1.1088x over previous
//
#include <hip/hip_runtime.h>
#include <hip/hip_bf16.h>

typedef __attribute__((ext_vector_type(8))) short bf16x8;
typedef __attribute__((ext_vector_type(4))) float f32x4;

static constexpr int Bb = 64;
static constexpr int Qq = 32;
static constexpr int LD = 4096;
static constexpr int Dd = 128;
static constexpr int SPLITS = 16;            // 1024 blocks = 4/CU = 16 waves/CU (same as R5)
static constexpr int CHUNK = LD / SPLITS;    // 256 tokens per block
static constexpr int TILE = 32;              // tokens per LDS tile
static constexpr int ITERS = CHUNK / TILE;   // 8
static constexpr int TILE_BYTES = TILE * Dd * 4;  // 16 KB fp32
static constexpr int ROW_BYTES = Dd * 4;     // 512 B per token

__device__ __forceinline__ short f2bf(float f) {
  __hip_bfloat16 h = __float2bfloat16(f);
  return *reinterpret_cast<short*>(&h);
}

__device__ __forceinline__ bf16x8 cvt8(float4 a, float4 b) {
  bf16x8 v;
  v[0] = f2bf(a.x); v[1] = f2bf(a.y); v[2] = f2bf(a.z); v[3] = f2bf(a.w);
  v[4] = f2bf(b.x); v[5] = f2bf(b.y); v[6] = f2bf(b.z); v[7] = f2bf(b.w);
  return v;
}

__device__ __forceinline__ void gload16(const void* g, void* l) {
  __builtin_amdgcn_global_load_lds(
      (const __attribute__((address_space(1))) void*)g,
      (__attribute__((address_space(3))) void*)l, 16, 0, 0);
}

// Stage 1, contiguity A/B vs R5: doc path goes global->LDS via width-16
// global_load_lds (each wave-instr = 1 KB fully contiguous at line level),
// double-buffered 2x16KB. LDS is written LINEARLY (HW rule) from a
// pre-swizzled global source; ds_read applies the same XOR (involution):
//   LDS[P] = global[P ^ ((rowof(P)&7)<<4)],  read at A' = A ^ ((rowof(A)&7)<<4).
// The XOR only permutes 16B units inside 128B windows -> global requests stay
// full-line contiguous; ds_read_b128 lands at the b128 bank floor (no 16-way).
__global__ __launch_bounds__(256, 4) void maxsim_stage1(
    const float* __restrict__ qe, const float* __restrict__ de,
    float* __restrict__ pmax) {
  __shared__ __align__(16) char lds[2][TILE_BYTES];

  const int blk  = blockIdx.x;
  const int b    = blk / SPLITS;
  const int s    = blk % SPLITS;
  const int wave = threadIdx.x >> 6;
  const int lane = threadIdx.x & 63;
  const int lcol = lane & 15;     // MFMA column slot
  const int lgrp = lane >> 4;     // MFMA k-group
  const int mt   = wave >> 1;     // this wave's 16-query M-tile (0/1)
  const int half = wave & 1;      // this wave's 16-token half of the 32-token tile

  const float* __restrict__ qb = qe + (size_t)b * Qq * Dd;
  const char*  __restrict__ dchunk =
      (const char*)(de + (size_t)b * LD * Dd) + (size_t)s * CHUNK * ROW_BYTES;

  // A fragment: one M-tile (16 query rows), registers for whole kernel.
  // Same lane->k rule as B, so any k-slot permutation cancels in the dot.
  bf16x8 afrag[4];
#pragma unroll
  for (int kb = 0; kb < 4; ++kb) {
    const float* p = qb + (size_t)(mt * 16 + lcol) * Dd + kb * 32 + lgrp * 8;
    afrag[kb] = cvt8(*reinterpret_cast<const float4*>(p),
                     *reinterpret_cast<const float4*>(p + 4));
  }

  // Stage tile `it` into buffer `bufi`: 4 instrs x 4 waves x 1KB, contiguous.
  auto STAGE = [&](int it, int bufi) {
    const char* itb = dchunk + (size_t)it * TILE_BYTES;
#pragma unroll
    for (int i = 0; i < 4; ++i) {
      unsigned P = (unsigned)(i * 4096 + wave * 1024 + lane * 16);
      unsigned G = P ^ (((P >> 9) & 7u) << 4);          // pre-swizzled source
      gload16(itb + G, &lds[bufi][i * 4096 + wave * 1024]);
    }
  };

  float mx[4];
#pragma unroll
  for (int i = 0; i < 4; ++i) mx[i] = -3.4e38f;

  const int row = half * 16 + lcol;                 // this lane's token row in tile
  const unsigned sw = ((unsigned)(lcol & 7)) << 4;  // row&7 == lcol&7 (half*16 ≡ 0 mod 8)

  STAGE(0, 0);
  __syncthreads();

  for (int it = 0; it < ITERS; ++it) {
    const int cur = it & 1;
    if (it + 1 < ITERS) STAGE(it + 1, cur ^ 1);     // issue next tile first (overlap)

    const char* base = &lds[cur][row * ROW_BYTES];
    f32x4 acc = {0.f, 0.f, 0.f, 0.f};
#pragma unroll
    for (int kb = 0; kb < 4; ++kb) {
      unsigned o0 = ((unsigned)(kb * 128 + lgrp * 32)) ^ sw;
      unsigned o1 = ((unsigned)(kb * 128 + lgrp * 32 + 16)) ^ sw;
      float4 f0 = *reinterpret_cast<const float4*>(base + o0);
      float4 f1 = *reinterpret_cast<const float4*>(base + o1);
      bf16x8 bf = cvt8(f0, f1);
      acc = __builtin_amdgcn_mfma_f32_16x16x32_bf16(afrag[kb], bf, acc, 0, 0, 0);
    }
    // C/D layout (m89-verified): col = lane&15 (doc token), row = lgrp*4+i (query).
#pragma unroll
    for (int i = 0; i < 4; ++i) mx[i] = fmaxf(mx[i], acc[i]);

    __syncthreads();  // drains staging vmcnt + protects buffer reuse
  }

  // Max over this wave's 16 doc-token columns = butterfly over low 4 lane bits.
#pragma unroll
  for (int off = 1; off < 16; off <<= 1)
#pragma unroll
    for (int i = 0; i < 4; ++i) mx[i] = fmaxf(mx[i], __shfl_xor(mx[i], off));

  __shared__ float smax[4][16];   // [wave = mt*2+half][q-row within M-tile]
  if (lcol == 0) {
#pragma unroll
    for (int i = 0; i < 4; ++i) smax[wave][lgrp * 4 + i] = mx[i];
  }
  __syncthreads();
  if (threadIdx.x < Qq) {
    const int qi = threadIdx.x;
    const int qmt = qi >> 4, qr = qi & 15;
    float m = fmaxf(smax[qmt * 2 + 0][qr], smax[qmt * 2 + 1][qr]);
    pmax[((size_t)b * SPLITS + s) * Qq + qi] = m;
  }
}

// Stage 2: out[b] = sum_q max_s pmax[b][s][q]. One wave per batch.
__global__ __launch_bounds__(64) void maxsim_stage2(
    const float* __restrict__ pmax, float* __restrict__ out) {
  const int b = blockIdx.x;
  const int lane = threadIdx.x;
  float v = 0.f;
  if (lane < Qq) {
    float m = -3.4e38f;
#pragma unroll
    for (int s = 0; s < SPLITS; ++s)
      m = fmaxf(m, pmax[((size_t)b * SPLITS + s) * Qq + lane]);
    v = m;
  }
#pragma unroll
  for (int off = 1; off < 64; off <<= 1) v += __shfl_xor(v, off);
  if (lane == 0) out[b] = v;
}

extern "C" void kernel_launch(void* const* d_in, const int* in_sizes, int n_in,
                              void* d_out, int out_size, void* d_ws, size_t ws_size,
                              hipStream_t stream) {
  const float* qe = (const float*)d_in[0];  // [64,32,128] f32
  const float* de = (const float*)d_in[1];  // [64,4096,128] f32
  float* out  = (float*)d_out;              // [64] f32
  float* pmax = (float*)d_ws;               // [64][16][32] f32 = 128 KB

  maxsim_stage1<<<Bb * SPLITS, 256, 0, stream>>>(qe, de, pmax);
  maxsim_stage2<<<Bb, 64, 0, stream>>>(pmax, out);
}